// Round 6
// baseline (469.884 us; speedup 1.0000x reference)
//
#include <hip/hip_runtime.h>

#define B_ 8
#define L_ 2048
#define D_ 512
#define BI 128            // i-rows per block
#define BJ 64
#define NJB (L_ / BJ)     // 32

typedef __attribute__((ext_vector_type(4))) float  floatx4;
typedef __attribute__((ext_vector_type(8))) _Float16 halfx8;
typedef __attribute__((ext_vector_type(4))) int    intx4;

#define KSCALE 0.51012599f  // log2(e)/sqrt(8): exp2-domain softmax

static __device__ __forceinline__ unsigned short f2h_bits(float x) {
  _Float16 h = (_Float16)x;
  return __builtin_bit_cast(unsigned short, h);
}

typedef __attribute__((address_space(1))) const unsigned short gus;
typedef __attribute__((address_space(3))) unsigned short lus;
static __device__ __forceinline__ void gld_lds16(const unsigned short* g,
                                                 unsigned short* l) {
  __builtin_amdgcn_global_load_lds((gus*)g, (lus*)l, 16, 0, 0);
}

// ---------------------------------------------------------------------------
// prep: Kh[b][l][d] = in*kw (f16);
//       Vfrag[b][jb][d16*2+kc][lane][e] = in*vw (f16, MFMA-B fragment order:
//         lane=(quad,ln16), elem e -> V[j = jb*64 + kc*32 + quad*8 + e]
//                                      [d = d16*16 + ln16])
//       Qh[b][l][d] = in*qw*KSCALE (f16, if ws fits).
// grid (L/64, D/64), 256 threads; batch loop inside -> weights read ONCE.
// (unchanged since round 4 — proven correct)
// ---------------------------------------------------------------------------
__global__ __launch_bounds__(256) void prep_kvq(const float* __restrict__ in,
                                                const float* __restrict__ qw,
                                                const float* __restrict__ kw,
                                                const float* __restrict__ vw,
                                                unsigned short* __restrict__ Kh,
                                                unsigned short* __restrict__ Vfrag,
                                                unsigned short* __restrict__ Qh,
                                                int has_qh) {
  const int lt = blockIdx.x * 64;   // j-tile (== jb*64)
  const int dt = blockIdx.y * 64;   // d-tile
  const int t  = threadIdx.x;
  __shared__ unsigned short vtile[64][66];  // [j][d], +2 pad

  float4 qv[4], kv[4], vv[4];
  #pragma unroll
  for (int i = 0; i < 4; ++i) {
    int c  = i * 256 + t;
    int r  = c >> 4;
    int c4 = (c & 15) * 4;
    size_t wi_ = (size_t)(lt + r) * D_ + (dt + c4);
    qv[i] = *(const float4*)(qw + wi_);
    kv[i] = *(const float4*)(kw + wi_);
    vv[i] = *(const float4*)(vw + wi_);
  }
  const int wv   = t >> 6;    // wave 0..3
  const int ln   = t & 63;
  const int q4   = ln >> 4;   // quad
  const int l16  = ln & 15;
  for (int b = 0; b < B_; ++b) {
    #pragma unroll
    for (int i = 0; i < 4; ++i) {
      int c  = i * 256 + t;
      int r  = c >> 4;
      int c4 = (c & 15) * 4;
      size_t gi = ((size_t)b * L_ + (lt + r)) * D_ + (dt + c4);
      float4 iv = *(const float4*)(in + gi);
      uint2 pk;
      pk.x = (unsigned int)f2h_bits(iv.x * kv[i].x) |
             ((unsigned int)f2h_bits(iv.y * kv[i].y) << 16);
      pk.y = (unsigned int)f2h_bits(iv.z * kv[i].z) |
             ((unsigned int)f2h_bits(iv.w * kv[i].w) << 16);
      *(uint2*)(Kh + gi) = pk;
      if (has_qh) {
        uint2 pq;
        pq.x = (unsigned int)f2h_bits(iv.x * qv[i].x * KSCALE) |
               ((unsigned int)f2h_bits(iv.y * qv[i].y * KSCALE) << 16);
        pq.y = (unsigned int)f2h_bits(iv.z * qv[i].z * KSCALE) |
               ((unsigned int)f2h_bits(iv.w * qv[i].w * KSCALE) << 16);
        *(uint2*)(Qh + gi) = pq;
      }
      vtile[r][c4 + 0] = f2h_bits(iv.x * vv[i].x);
      vtile[r][c4 + 1] = f2h_bits(iv.y * vv[i].y);
      vtile[r][c4 + 2] = f2h_bits(iv.z * vv[i].z);
      vtile[r][c4 + 3] = f2h_bits(iv.w * vv[i].w);
    }
    __syncthreads();
    #pragma unroll
    for (int i = 0; i < 2; ++i) {
      int ch  = wv * 2 + i;        // 0..7
      int dtl = ch >> 1;           // local d-tile 0..3
      int kc  = ch & 1;            // j-half 0..1
      int ov[4];
      #pragma unroll
      for (int j = 0; j < 4; ++j) {
        int e0 = 2 * j;
        ov[j] = (int)((unsigned int)vtile[kc * 32 + q4 * 8 + e0][dtl * 16 + l16] |
                      ((unsigned int)vtile[kc * 32 + q4 * 8 + e0 + 1][dtl * 16 + l16] << 16));
      }
      intx4 o; o[0] = ov[0]; o[1] = ov[1]; o[2] = ov[2]; o[3] = ov[3];
      size_t off = ((((size_t)b * NJB + (lt >> 6)) * 64) +
                    ((size_t)(dt >> 4) + dtl) * 2 + kc) * 512 + (size_t)ln * 8;
      *(intx4*)(Vfrag + off) = o;
    }
    __syncthreads();
  }
}

// ---------------------------------------------------------------------------
// flash v7 — LDS-traffic-bound fix (rounds 0-5 audit): rows/wave 16 -> 32
// halves K-fragment ds_read traffic (each 1-KB B-frag now feeds 2 MFMAs).
// 4 waves x 256 thr, __launch_bounds__(256,1): 1 wave/SIMD -> 512-VGPR
// budget; peak demand qf[2][16]=128 + O[8][4]=128 + s 32 + state ~ 330,
// spill-proof (rounds 1-3 failure mode was 128-reg Q at the 256 cap).
//  grid 256 = b(&7, XCD-pin) x i-tile(16, BI=128) x dh(2, 256-wide D-half).
//  QK^T: wave w owns rows w*32..+32 (2 A-tiles share every K B-frag read),
//        full 64 j -> softmax WAVE-LOCAL. S duplicated across dh-blocks.
//  PV:   wave w owns UNIQUE 64-wide d-strip; V staged once (32 KB/jb).
//  K: double-buffered LDS via global_load_lds (XOR^(r&15) pre-swizzled src).
//  2 barriers/jb. RULE-20: all qf/s/O/vf loops fully unrolled.
// ---------------------------------------------------------------------------
__global__ __launch_bounds__(256, 1) void flash4(const float* __restrict__ in,
                                                 const float* __restrict__ qw,
                                                 const unsigned short* __restrict__ Kh,
                                                 const unsigned short* __restrict__ Vfrag,
                                                 const unsigned short* __restrict__ Qh,
                                                 float* __restrict__ out,
                                                 int has_qh) {
  const int bid  = blockIdx.x;
  const int b    = bid & 7;            // batch == XCD (round-robin dispatch)
  const int t2   = bid >> 3;
  const int it_  = t2 & 15;            // i-tile
  const int dh   = t2 >> 4;            // D-half 0..1
  const int i0   = it_ * BI;
  const int tid  = threadIdx.x;
  const int w    = tid >> 6;           // wave 0..3
  const int lane = tid & 63;
  const int ln16 = lane & 15;
  const int quad = lane >> 4;

  __shared__ unsigned short Ksh[2][BJ][D_];  // 128 KB double-buffered
  __shared__ unsigned short Psh[BI][72];     // 18.4 KB
  __shared__ float Alsh[BI];                 // per-jb rescale alpha
  __shared__ float Lsh[BI];                  // final l

  // ---- Q fragments: rows i0 + w*32 + it*16 + ln16, full K, A-layout ----
  halfx8 qf[2][16];
  if (has_qh) {
    #pragma unroll
    for (int it = 0; it < 2; ++it) {
      const unsigned short* qp =
          Qh + ((size_t)b * L_ + (i0 + w * 32 + it * 16 + ln16)) * D_;
      #pragma unroll
      for (int ks = 0; ks < 16; ++ks)
        qf[it][ks] = *(const halfx8*)(qp + ks * 32 + quad * 8);
    }
  } else {
    #pragma unroll
    for (int it = 0; it < 2; ++it) {
      const int qi = i0 + w * 32 + it * 16 + ln16;
      const float* ip = in + ((size_t)b * L_ + qi) * D_;
      const float* wp = qw + (size_t)qi * D_;
      #pragma unroll
      for (int ks = 0; ks < 16; ++ks) {
        int d0 = ks * 32 + quad * 8;
        float4 a0 = *(const float4*)(ip + d0);
        float4 a1 = *(const float4*)(ip + d0 + 4);
        float4 w0 = *(const float4*)(wp + d0);
        float4 w1 = *(const float4*)(wp + d0 + 4);
        halfx8 q;
        q[0] = (_Float16)(a0.x * w0.x * KSCALE);
        q[1] = (_Float16)(a0.y * w0.y * KSCALE);
        q[2] = (_Float16)(a0.z * w0.z * KSCALE);
        q[3] = (_Float16)(a0.w * w0.w * KSCALE);
        q[4] = (_Float16)(a1.x * w1.x * KSCALE);
        q[5] = (_Float16)(a1.y * w1.y * KSCALE);
        q[6] = (_Float16)(a1.z * w1.z * KSCALE);
        q[7] = (_Float16)(a1.w * w1.w * KSCALE);
        qf[it][ks] = q;
      }
    }
  }

  // softmax state: row = w*32 + it*16 + quad*4 + r
  float m_r[2][4], l_r[2][4];
  #pragma unroll
  for (int it = 0; it < 2; ++it)
    #pragma unroll
    for (int r = 0; r < 4; ++r) { m_r[it][r] = -1e30f; l_r[it][r] = 0.f; }
  // O: all 128 rows x this wave's 64-wide d-strip
  floatx4 O[8][4];
  #pragma unroll
  for (int rt = 0; rt < 8; ++rt)
    #pragma unroll
    for (int dt = 0; dt < 4; ++dt) O[rt][dt] = (floatx4){0.f, 0.f, 0.f, 0.f};

  // ---- prologue: DMA K tile 0 into buf0 (pre-swizzled source) ----
  {
    const unsigned short* kb = Kh + ((size_t)b * L_ + w * 16) * D_;
    #pragma unroll
    for (int k = 0; k < 16; ++k) {
      int r = w * 16 + k;
      gld_lds16(kb + (size_t)k * D_ + ((lane ^ (r & 15)) << 3), &Ksh[0][r][0]);
    }
  }
  __syncthreads();

  int buf = 0;
  for (int jb = 0; jb < NJB; ++jb) {
    // ======== phase 1: QK^T (32 rows x 64 j) + wave-local softmax ========
    floatx4 s[2][4];
    #pragma unroll
    for (int it = 0; it < 2; ++it)
      #pragma unroll
      for (int jt = 0; jt < 4; ++jt) s[it][jt] = (floatx4){0.f, 0.f, 0.f, 0.f};
    #pragma unroll
    for (int ks = 0; ks < 16; ++ks) {
      #pragma unroll
      for (int jt = 0; jt < 4; ++jt) {
        halfx8 bk = *(const halfx8*)(
            &Ksh[buf][jt * 16 + ln16][((ks * 4 + quad) ^ ln16) << 3]);
        s[0][jt] = __builtin_amdgcn_mfma_f32_16x16x32_f16(qf[0][ks], bk, s[0][jt], 0, 0, 0);
        s[1][jt] = __builtin_amdgcn_mfma_f32_16x16x32_f16(qf[1][ks], bk, s[1][jt], 0, 0, 0);
      }
    }
    #pragma unroll
    for (int it = 0; it < 2; ++it) {
      #pragma unroll
      for (int r = 0; r < 4; ++r) {
        float mx = fmaxf(fmaxf(s[it][0][r], s[it][1][r]),
                         fmaxf(s[it][2][r], s[it][3][r]));
        #pragma unroll
        for (int off = 1; off < 16; off <<= 1) mx = fmaxf(mx, __shfl_xor(mx, off));
        float mn = fmaxf(m_r[it][r], mx);
        float al = exp2f(m_r[it][r] - mn);   // 1.0 when no update
        m_r[it][r] = mn;
        int row = w * 32 + it * 16 + quad * 4 + r;
        float ls = 0.f;
        #pragma unroll
        for (int jt = 0; jt < 4; ++jt) {
          float p = exp2f(s[it][jt][r] - mn);
          Psh[row][jt * 16 + ln16] = f2h_bits(p);
          ls += p;
        }
        #pragma unroll
        for (int off = 1; off < 16; off <<= 1) ls += __shfl_xor(ls, off);
        l_r[it][r] = l_r[it][r] * al + ls;
        if (ln16 == 0) Alsh[row] = al;
      }
    }
    __syncthreads();  // barA: Psh/Alsh ready; Ksh[buf] consumed

    // ======== phase 2: PV over this wave's 64-wide d-strip ========
    halfx8 vf[4][2];
    {
      const unsigned short* vb =
          Vfrag + (((size_t)b * NJB + jb) * 64) * 512 + (size_t)lane * 8;
      #pragma unroll
      for (int dt = 0; dt < 4; ++dt)
        #pragma unroll
        for (int kc = 0; kc < 2; ++kc)
          vf[dt][kc] = *(const halfx8*)(
              vb + (size_t)(((dh * 16 + w * 4 + dt) * 2 + kc)) * 512);
    }
    if (jb + 1 < NJB) {
      const unsigned short* kb =
          Kh + ((size_t)b * L_ + (jb + 1) * BJ + w * 16) * D_;
      #pragma unroll
      for (int k = 0; k < 16; ++k) {
        int r = w * 16 + k;
        gld_lds16(kb + (size_t)k * D_ + ((lane ^ (r & 15)) << 3),
                  &Ksh[buf ^ 1][r][0]);
      }
    }
    // rescale O by per-row alpha (broadcast reads, conflict-free)
    #pragma unroll
    for (int rt = 0; rt < 8; ++rt) {
      float4 alv = *(const float4*)(&Alsh[rt * 16 + quad * 4]);
      #pragma unroll
      for (int dt = 0; dt < 4; ++dt) {
        O[rt][dt][0] *= alv.x; O[rt][dt][1] *= alv.y;
        O[rt][dt][2] *= alv.z; O[rt][dt][3] *= alv.w;
      }
    }
    // O += P V  (pf read once per (rt,kc), reused across 4 d-tiles)
    #pragma unroll
    for (int rt = 0; rt < 8; ++rt) {
      #pragma unroll
      for (int kc = 0; kc < 2; ++kc) {
        halfx8 pf = *(const halfx8*)(&Psh[rt * 16 + ln16][kc * 32 + quad * 8]);
        O[rt][0] = __builtin_amdgcn_mfma_f32_16x16x32_f16(pf, vf[0][kc], O[rt][0], 0, 0, 0);
        O[rt][1] = __builtin_amdgcn_mfma_f32_16x16x32_f16(pf, vf[1][kc], O[rt][1], 0, 0, 0);
        O[rt][2] = __builtin_amdgcn_mfma_f32_16x16x32_f16(pf, vf[2][kc], O[rt][2], 0, 0, 0);
        O[rt][3] = __builtin_amdgcn_mfma_f32_16x16x32_f16(pf, vf[3][kc], O[rt][3], 0, 0, 0);
      }
    }
    __syncthreads();  // barB: vmcnt(0) drain -> next K landed; Psh/Alsh free
    buf ^= 1;
  }

  // ---- epilogue: publish l, divide, store this block's D-half ----
  if (ln16 == 0) {
    #pragma unroll
    for (int it = 0; it < 2; ++it)
      #pragma unroll
      for (int r = 0; r < 4; ++r)
        Lsh[w * 32 + it * 16 + quad * 4 + r] = l_r[it][r];
  }
  __syncthreads();
  #pragma unroll
  for (int rt = 0; rt < 8; ++rt) {
    float4 lv = *(const float4*)(&Lsh[rt * 16 + quad * 4]);
    float i0v = 1.0f / lv.x, i1v = 1.0f / lv.y;
    float i2v = 1.0f / lv.z, i3v = 1.0f / lv.w;
    float* op = out + ((size_t)b * L_ + i0 + rt * 16 + quad * 4) * D_ +
                dh * 256 + w * 64 + ln16;
    #pragma unroll
    for (int dt = 0; dt < 4; ++dt) {
      op[(size_t)0 * D_ + dt * 16] = O[rt][dt][0] * i0v;
      op[(size_t)1 * D_ + dt * 16] = O[rt][dt][1] * i1v;
      op[(size_t)2 * D_ + dt * 16] = O[rt][dt][2] * i2v;
      op[(size_t)3 * D_ + dt * 16] = O[rt][dt][3] * i3v;
    }
  }
}

// ---------------------------------------------------------------------------
extern "C" void kernel_launch(void* const* d_in, const int* in_sizes, int n_in,
                              void* d_out, int out_size, void* d_ws, size_t ws_size,
                              hipStream_t stream) {
  const float* in = (const float*)d_in[0];
  const float* qw = (const float*)d_in[1];
  const float* kw = (const float*)d_in[2];
  const float* vw = (const float*)d_in[3];
  float* out = (float*)d_out;

  const size_t seg = (size_t)B_ * L_ * D_;          // elements per f16 tensor
  unsigned short* Kh = (unsigned short*)d_ws;       // 16.78 MB
  unsigned short* Vf = Kh + seg;                    // 16.78 MB (fragment order)
  unsigned short* Qh = Vf + seg;                    // 16.78 MB (optional)
  const int has_qh = (ws_size >= 3 * seg * sizeof(unsigned short)) ? 1 : 0;

  dim3 gp(L_ / 64, D_ / 64);
  prep_kvq<<<gp, dim3(256), 0, stream>>>(in, qw, kw, vw, Kh, Vf, Qh, has_qh);
  flash4<<<dim3(256), dim3(256), 0, stream>>>(in, qw, Kh, Vf, Qh, out, has_qh);
}

// Round 7
// 255.117 us; speedup vs baseline: 1.8418x; 1.8418x over previous
//
#include <hip/hip_runtime.h>

#define B_ 8
#define L_ 2048
#define D_ 512
#define BI 128            // i-rows per block
#define BJ 64
#define NJB (L_ / BJ)     // 32

typedef __attribute__((ext_vector_type(4))) float  floatx4;
typedef __attribute__((ext_vector_type(8))) _Float16 halfx8;
typedef __attribute__((ext_vector_type(4))) int    intx4;

#define KSCALE 0.51012599f  // log2(e)/sqrt(8): exp2-domain softmax

static __device__ __forceinline__ unsigned short f2h_bits(float x) {
  _Float16 h = (_Float16)x;
  return __builtin_bit_cast(unsigned short, h);
}

typedef __attribute__((address_space(1))) const unsigned short gus;
typedef __attribute__((address_space(3))) unsigned short lus;
static __device__ __forceinline__ void gld_lds16(const unsigned short* g,
                                                 unsigned short* l) {
  __builtin_amdgcn_global_load_lds((gus*)g, (lus*)l, 16, 0, 0);
}

// ---------------------------------------------------------------------------
// prep: Kh[b][l][d] = in*kw (f16);
//       Vfrag[b][jb][d16*2+kc][lane][e] = in*vw (f16, MFMA-B fragment order:
//         lane=(quad,ln16), elem e -> V[j = jb*64 + kc*32 + quad*8 + e]
//                                      [d = d16*16 + ln16])
//       Qh[b][l][d] = in*qw*KSCALE (f16, if ws fits).
// grid (L/64, D/64), 256 threads; batch loop inside -> weights read ONCE.
// (unchanged since round 4 — proven correct)
// ---------------------------------------------------------------------------
__global__ __launch_bounds__(256) void prep_kvq(const float* __restrict__ in,
                                                const float* __restrict__ qw,
                                                const float* __restrict__ kw,
                                                const float* __restrict__ vw,
                                                unsigned short* __restrict__ Kh,
                                                unsigned short* __restrict__ Vfrag,
                                                unsigned short* __restrict__ Qh,
                                                int has_qh) {
  const int lt = blockIdx.x * 64;   // j-tile (== jb*64)
  const int dt = blockIdx.y * 64;   // d-tile
  const int t  = threadIdx.x;
  __shared__ unsigned short vtile[64][66];  // [j][d], +2 pad

  float4 qv[4], kv[4], vv[4];
  #pragma unroll
  for (int i = 0; i < 4; ++i) {
    int c  = i * 256 + t;
    int r  = c >> 4;
    int c4 = (c & 15) * 4;
    size_t wi_ = (size_t)(lt + r) * D_ + (dt + c4);
    qv[i] = *(const float4*)(qw + wi_);
    kv[i] = *(const float4*)(kw + wi_);
    vv[i] = *(const float4*)(vw + wi_);
  }
  const int wv   = t >> 6;    // wave 0..3
  const int ln   = t & 63;
  const int q4   = ln >> 4;   // quad
  const int l16  = ln & 15;
  for (int b = 0; b < B_; ++b) {
    #pragma unroll
    for (int i = 0; i < 4; ++i) {
      int c  = i * 256 + t;
      int r  = c >> 4;
      int c4 = (c & 15) * 4;
      size_t gi = ((size_t)b * L_ + (lt + r)) * D_ + (dt + c4);
      float4 iv = *(const float4*)(in + gi);
      uint2 pk;
      pk.x = (unsigned int)f2h_bits(iv.x * kv[i].x) |
             ((unsigned int)f2h_bits(iv.y * kv[i].y) << 16);
      pk.y = (unsigned int)f2h_bits(iv.z * kv[i].z) |
             ((unsigned int)f2h_bits(iv.w * kv[i].w) << 16);
      *(uint2*)(Kh + gi) = pk;
      if (has_qh) {
        uint2 pq;
        pq.x = (unsigned int)f2h_bits(iv.x * qv[i].x * KSCALE) |
               ((unsigned int)f2h_bits(iv.y * qv[i].y * KSCALE) << 16);
        pq.y = (unsigned int)f2h_bits(iv.z * qv[i].z * KSCALE) |
               ((unsigned int)f2h_bits(iv.w * qv[i].w * KSCALE) << 16);
        *(uint2*)(Qh + gi) = pq;
      }
      vtile[r][c4 + 0] = f2h_bits(iv.x * vv[i].x);
      vtile[r][c4 + 1] = f2h_bits(iv.y * vv[i].y);
      vtile[r][c4 + 2] = f2h_bits(iv.z * vv[i].z);
      vtile[r][c4 + 3] = f2h_bits(iv.w * vv[i].w);
    }
    __syncthreads();
    #pragma unroll
    for (int i = 0; i < 2; ++i) {
      int ch  = wv * 2 + i;        // 0..7
      int dtl = ch >> 1;           // local d-tile 0..3
      int kc  = ch & 1;            // j-half 0..1
      int ov[4];
      #pragma unroll
      for (int j = 0; j < 4; ++j) {
        int e0 = 2 * j;
        ov[j] = (int)((unsigned int)vtile[kc * 32 + q4 * 8 + e0][dtl * 16 + l16] |
                      ((unsigned int)vtile[kc * 32 + q4 * 8 + e0 + 1][dtl * 16 + l16] << 16));
      }
      intx4 o; o[0] = ov[0]; o[1] = ov[1]; o[2] = ov[2]; o[3] = ov[3];
      size_t off = ((((size_t)b * NJB + (lt >> 6)) * 64) +
                    ((size_t)(dt >> 4) + dtl) * 2 + kc) * 512 + (size_t)ln * 8;
      *(intx4*)(Vfrag + off) = o;
    }
    __syncthreads();
  }
}

// ---------------------------------------------------------------------------
// flash v8 = round-5 structure (verified 171 us) + latency code-motion:
//  * V-loads and next-K DMA issued at TOP of phase 1 -> their ~300-900 cyc
//    latency drains at barA under the 8k-cyc QK^T+softmax phase instead of
//    serializing phase 2 (G15/T14 within the existing 2-barrier structure).
//  * s_setprio(1) around both MFMA clusters (T5, m191 attn +4-7%).
//  grid 256 = b(&7, XCD-pin) x i-tile(16, BI=128) x dh(2, 256-wide D-half).
//  8 waves x 512 thr, __launch_bounds__(512,2) -> 256-VGPR cap, ~140 used.
//  QK^T: wave w owns UNIQUE 16-row Q A-tile (qf[16]=64 VGPR, full K=512),
//        full 64 j -> softmax WAVE-LOCAL. S duplicated across dh-blocks.
//  PV:   wave w owns UNIQUE 32-wide d-strip; V staged once per block.
//  K: double-buffered LDS via global_load_lds (XOR^(r&15) pre-swizzled src).
//  Round-6 lesson: 32 rows/wave needs 128 Q-regs -> breaches the 256 arch
//  cap (spills; compiler won't overflow to AGPRs). 16 rows/wave is optimal.
//  RULE-20: all qf/s/O/vf loops fully unrolled.
// ---------------------------------------------------------------------------
__global__ __launch_bounds__(512, 2) void flash8(const float* __restrict__ in,
                                                 const float* __restrict__ qw,
                                                 const unsigned short* __restrict__ Kh,
                                                 const unsigned short* __restrict__ Vfrag,
                                                 const unsigned short* __restrict__ Qh,
                                                 float* __restrict__ out,
                                                 int has_qh) {
  const int bid  = blockIdx.x;
  const int b    = bid & 7;            // batch == XCD (round-robin dispatch)
  const int t2   = bid >> 3;
  const int it_  = t2 & 15;            // i-tile
  const int dh   = t2 >> 4;            // D-half 0..1
  const int i0   = it_ * BI;
  const int tid  = threadIdx.x;
  const int w    = tid >> 6;
  const int lane = tid & 63;
  const int ln16 = lane & 15;
  const int quad = lane >> 4;

  __shared__ unsigned short Ksh[2][BJ][D_];  // 128 KB double-buffered
  __shared__ unsigned short Psh[BI][72];     // 18.4 KB
  __shared__ float Alsh[BI];                 // per-jb rescale alpha
  __shared__ float Lsh[BI];                  // final l

  // ---- Q fragments: rows i0 + w*16 + ln16, full K, A-layout ----
  halfx8 qf[16];
  if (has_qh) {
    const unsigned short* qp =
        Qh + ((size_t)b * L_ + (i0 + w * 16 + ln16)) * D_;
    #pragma unroll
    for (int ks = 0; ks < 16; ++ks)
      qf[ks] = *(const halfx8*)(qp + ks * 32 + quad * 8);
  } else {
    const int qi = i0 + w * 16 + ln16;
    const float* ip = in + ((size_t)b * L_ + qi) * D_;
    const float* wp = qw + (size_t)qi * D_;
    #pragma unroll
    for (int ks = 0; ks < 16; ++ks) {
      int d0 = ks * 32 + quad * 8;
      float4 a0 = *(const float4*)(ip + d0);
      float4 a1 = *(const float4*)(ip + d0 + 4);
      float4 w0 = *(const float4*)(wp + d0);
      float4 w1 = *(const float4*)(wp + d0 + 4);
      halfx8 q;
      q[0] = (_Float16)(a0.x * w0.x * KSCALE);
      q[1] = (_Float16)(a0.y * w0.y * KSCALE);
      q[2] = (_Float16)(a0.z * w0.z * KSCALE);
      q[3] = (_Float16)(a0.w * w0.w * KSCALE);
      q[4] = (_Float16)(a1.x * w1.x * KSCALE);
      q[5] = (_Float16)(a1.y * w1.y * KSCALE);
      q[6] = (_Float16)(a1.z * w1.z * KSCALE);
      q[7] = (_Float16)(a1.w * w1.w * KSCALE);
      qf[ks] = q;
    }
  }

  // softmax state for this wave's 16 rows (row = w*16 + quad*4 + r)
  float m_r[4], l_r[4];
  #pragma unroll
  for (int r = 0; r < 4; ++r) { m_r[r] = -1e30f; l_r[r] = 0.f; }
  // O accumulator: all 128 rows x this wave's 32-wide d-strip
  floatx4 O[8][2];
  #pragma unroll
  for (int rt = 0; rt < 8; ++rt) {
    O[rt][0] = (floatx4){0.f, 0.f, 0.f, 0.f};
    O[rt][1] = (floatx4){0.f, 0.f, 0.f, 0.f};
  }

  // ---- prologue: DMA K tile 0 into buf0 (pre-swizzled source) ----
  {
    const unsigned short* kb = Kh + ((size_t)b * L_ + w * 8) * D_;
    #pragma unroll
    for (int k = 0; k < 8; ++k) {
      int r = w * 8 + k;
      gld_lds16(kb + (size_t)k * D_ + ((lane ^ (r & 15)) << 3), &Ksh[0][r][0]);
    }
  }
  __syncthreads();

  int buf = 0;
  for (int jb = 0; jb < NJB; ++jb) {
    // ---- prefetch issue (drains at barA, hidden under QK^T+softmax) ----
    // V fragments for phase 2 (registers, 1 KB lane-contiguous each):
    halfx8 vf[2][2];
    {
      const unsigned short* vb =
          Vfrag + (((size_t)b * NJB + jb) * 64) * 512 + (size_t)lane * 8;
      #pragma unroll
      for (int dt = 0; dt < 2; ++dt)
        #pragma unroll
        for (int kc = 0; kc < 2; ++kc)
          vf[dt][kc] = *(const halfx8*)(
              vb + (size_t)(((dh * 16 + w * 2 + dt) * 2 + kc)) * 512);
    }
    // next K tile DMA into the other buffer (last readers of buf^1 finished
    // before barA of the previous iteration -> no race):
    if (jb + 1 < NJB) {
      const unsigned short* kb =
          Kh + ((size_t)b * L_ + (jb + 1) * BJ + w * 8) * D_;
      #pragma unroll
      for (int k = 0; k < 8; ++k) {
        int r = w * 8 + k;
        gld_lds16(kb + (size_t)k * D_ + ((lane ^ (r & 15)) << 3),
                  &Ksh[buf ^ 1][r][0]);
      }
    }

    // ======== phase 1: full QK^T (16 rows x 64 j) + wave-local softmax ====
    floatx4 s[4];
    s[0] = (floatx4){0.f, 0.f, 0.f, 0.f};
    s[1] = (floatx4){0.f, 0.f, 0.f, 0.f};
    s[2] = (floatx4){0.f, 0.f, 0.f, 0.f};
    s[3] = (floatx4){0.f, 0.f, 0.f, 0.f};
    __builtin_amdgcn_s_setprio(1);
    #pragma unroll
    for (int ks = 0; ks < 16; ++ks) {
      #pragma unroll
      for (int jt = 0; jt < 4; ++jt) {
        halfx8 bk = *(const halfx8*)(
            &Ksh[buf][jt * 16 + ln16][((ks * 4 + quad) ^ ln16) << 3]);
        s[jt] = __builtin_amdgcn_mfma_f32_16x16x32_f16(qf[ks], bk, s[jt], 0, 0, 0);
      }
    }
    __builtin_amdgcn_s_setprio(0);
    #pragma unroll
    for (int r = 0; r < 4; ++r) {
      float mx = fmaxf(fmaxf(s[0][r], s[1][r]), fmaxf(s[2][r], s[3][r]));
      #pragma unroll
      for (int off = 1; off < 16; off <<= 1) mx = fmaxf(mx, __shfl_xor(mx, off));
      float mn = fmaxf(m_r[r], mx);
      float al = exp2f(m_r[r] - mn);   // 1.0 when no update, 0 on first tile
      m_r[r] = mn;
      int row = w * 16 + quad * 4 + r;
      float ls = 0.f;
      #pragma unroll
      for (int jt = 0; jt < 4; ++jt) {
        float p = exp2f(s[jt][r] - mn);
        Psh[row][jt * 16 + ln16] = f2h_bits(p);
        ls += p;
      }
      #pragma unroll
      for (int off = 1; off < 16; off <<= 1) ls += __shfl_xor(ls, off);
      l_r[r] = l_r[r] * al + ls;
      if (ln16 == 0) Alsh[row] = al;
    }
    __syncthreads();  // barA: Psh/Alsh ready; V+K prefetch drained; Ksh[buf] consumed

    // ======== phase 2: PV over this wave's 32-wide d-strip ========
    // rescale O by per-row alpha (broadcast reads, conflict-free)
    #pragma unroll
    for (int rt = 0; rt < 8; ++rt) {
      float4 alv = *(const float4*)(&Alsh[rt * 16 + quad * 4]);
      #pragma unroll
      for (int dt = 0; dt < 2; ++dt) {
        O[rt][dt][0] *= alv.x; O[rt][dt][1] *= alv.y;
        O[rt][dt][2] *= alv.z; O[rt][dt][3] *= alv.w;
      }
    }
    // O += P V
    __builtin_amdgcn_s_setprio(1);
    #pragma unroll
    for (int rt = 0; rt < 8; ++rt) {
      #pragma unroll
      for (int kc = 0; kc < 2; ++kc) {
        halfx8 pf = *(const halfx8*)(&Psh[rt * 16 + ln16][kc * 32 + quad * 8]);
        O[rt][0] = __builtin_amdgcn_mfma_f32_16x16x32_f16(pf, vf[0][kc], O[rt][0], 0, 0, 0);
        O[rt][1] = __builtin_amdgcn_mfma_f32_16x16x32_f16(pf, vf[1][kc], O[rt][1], 0, 0, 0);
      }
    }
    __builtin_amdgcn_s_setprio(0);
    __syncthreads();  // barB: Psh/Alsh free for next iteration
    buf ^= 1;
  }

  // ---- epilogue: publish l, divide, store this block's D-half ----
  if (ln16 == 0) {
    #pragma unroll
    for (int r = 0; r < 4; ++r) Lsh[w * 16 + quad * 4 + r] = l_r[r];
  }
  __syncthreads();
  #pragma unroll
  for (int rt = 0; rt < 8; ++rt) {
    float4 lv = *(const float4*)(&Lsh[rt * 16 + quad * 4]);
    float i0v = 1.0f / lv.x, i1v = 1.0f / lv.y;
    float i2v = 1.0f / lv.z, i3v = 1.0f / lv.w;
    float* op = out + ((size_t)b * L_ + i0 + rt * 16 + quad * 4) * D_ +
                dh * 256 + w * 32 + ln16;
    #pragma unroll
    for (int dt = 0; dt < 2; ++dt) {
      op[(size_t)0 * D_ + dt * 16] = O[rt][dt][0] * i0v;
      op[(size_t)1 * D_ + dt * 16] = O[rt][dt][1] * i1v;
      op[(size_t)2 * D_ + dt * 16] = O[rt][dt][2] * i2v;
      op[(size_t)3 * D_ + dt * 16] = O[rt][dt][3] * i3v;
    }
  }
}

// ---------------------------------------------------------------------------
extern "C" void kernel_launch(void* const* d_in, const int* in_sizes, int n_in,
                              void* d_out, int out_size, void* d_ws, size_t ws_size,
                              hipStream_t stream) {
  const float* in = (const float*)d_in[0];
  const float* qw = (const float*)d_in[1];
  const float* kw = (const float*)d_in[2];
  const float* vw = (const float*)d_in[3];
  float* out = (float*)d_out;

  const size_t seg = (size_t)B_ * L_ * D_;          // elements per f16 tensor
  unsigned short* Kh = (unsigned short*)d_ws;       // 16.78 MB
  unsigned short* Vf = Kh + seg;                    // 16.78 MB (fragment order)
  unsigned short* Qh = Vf + seg;                    // 16.78 MB (optional)
  const int has_qh = (ws_size >= 3 * seg * sizeof(unsigned short)) ? 1 : 0;

  dim3 gp(L_ / 64, D_ / 64);
  prep_kvq<<<gp, dim3(256), 0, stream>>>(in, qw, kw, vw, Kh, Vf, Qh, has_qh);
  flash8<<<dim3(256), dim3(512), 0, stream>>>(in, qw, Kh, Vf, Qh, out, has_qh);
}

// Round 8
// 247.814 us; speedup vs baseline: 1.8961x; 1.0295x over previous
//
#include <hip/hip_runtime.h>

#define B_ 8
#define L_ 2048
#define D_ 512
#define BI 128            // i-rows per block
#define BJ 64
#define NJB (L_ / BJ)     // 32

typedef __attribute__((ext_vector_type(4))) float  floatx4;
typedef __attribute__((ext_vector_type(8))) _Float16 halfx8;
typedef __attribute__((ext_vector_type(4))) int    intx4;

#define KSCALE 0.51012599f  // log2(e)/sqrt(8): exp2-domain softmax

static __device__ __forceinline__ unsigned short f2h_bits(float x) {
  _Float16 h = (_Float16)x;
  return __builtin_bit_cast(unsigned short, h);
}

typedef __attribute__((address_space(1))) const unsigned short gus;
typedef __attribute__((address_space(3))) unsigned short lus;
static __device__ __forceinline__ void gld_lds16(const unsigned short* g,
                                                 unsigned short* l) {
  __builtin_amdgcn_global_load_lds((gus*)g, (lus*)l, 16, 0, 0);
}

// ---------------------------------------------------------------------------
// prep: Kh[b][l][d] = in*kw (f16);
//       Vfrag[b][jb][d16*2+kc][lane][e] = in*vw (f16, MFMA-B fragment order:
//         lane=(quad,ln16), elem e -> V[j = jb*64 + kc*32 + quad*8 + e]
//                                      [d = d16*16 + ln16])
//       Qh[b][l][d] = in*qw*KSCALE (f16, if ws fits).
// grid (L/64, D/64), 256 threads; batch loop inside -> weights read ONCE.
// (unchanged since round 4 — proven correct)
// ---------------------------------------------------------------------------
__global__ __launch_bounds__(256) void prep_kvq(const float* __restrict__ in,
                                                const float* __restrict__ qw,
                                                const float* __restrict__ kw,
                                                const float* __restrict__ vw,
                                                unsigned short* __restrict__ Kh,
                                                unsigned short* __restrict__ Vfrag,
                                                unsigned short* __restrict__ Qh,
                                                int has_qh) {
  const int lt = blockIdx.x * 64;   // j-tile (== jb*64)
  const int dt = blockIdx.y * 64;   // d-tile
  const int t  = threadIdx.x;
  __shared__ unsigned short vtile[64][66];  // [j][d], +2 pad

  float4 qv[4], kv[4], vv[4];
  #pragma unroll
  for (int i = 0; i < 4; ++i) {
    int c  = i * 256 + t;
    int r  = c >> 4;
    int c4 = (c & 15) * 4;
    size_t wi_ = (size_t)(lt + r) * D_ + (dt + c4);
    qv[i] = *(const float4*)(qw + wi_);
    kv[i] = *(const float4*)(kw + wi_);
    vv[i] = *(const float4*)(vw + wi_);
  }
  const int wv   = t >> 6;    // wave 0..3
  const int ln   = t & 63;
  const int q4   = ln >> 4;   // quad
  const int l16  = ln & 15;
  for (int b = 0; b < B_; ++b) {
    #pragma unroll
    for (int i = 0; i < 4; ++i) {
      int c  = i * 256 + t;
      int r  = c >> 4;
      int c4 = (c & 15) * 4;
      size_t gi = ((size_t)b * L_ + (lt + r)) * D_ + (dt + c4);
      float4 iv = *(const float4*)(in + gi);
      uint2 pk;
      pk.x = (unsigned int)f2h_bits(iv.x * kv[i].x) |
             ((unsigned int)f2h_bits(iv.y * kv[i].y) << 16);
      pk.y = (unsigned int)f2h_bits(iv.z * kv[i].z) |
             ((unsigned int)f2h_bits(iv.w * kv[i].w) << 16);
      *(uint2*)(Kh + gi) = pk;
      if (has_qh) {
        uint2 pq;
        pq.x = (unsigned int)f2h_bits(iv.x * qv[i].x * KSCALE) |
               ((unsigned int)f2h_bits(iv.y * qv[i].y * KSCALE) << 16);
        pq.y = (unsigned int)f2h_bits(iv.z * qv[i].z * KSCALE) |
               ((unsigned int)f2h_bits(iv.w * qv[i].w * KSCALE) << 16);
        *(uint2*)(Qh + gi) = pq;
      }
      vtile[r][c4 + 0] = f2h_bits(iv.x * vv[i].x);
      vtile[r][c4 + 1] = f2h_bits(iv.y * vv[i].y);
      vtile[r][c4 + 2] = f2h_bits(iv.z * vv[i].z);
      vtile[r][c4 + 3] = f2h_bits(iv.w * vv[i].w);
    }
    __syncthreads();
    #pragma unroll
    for (int i = 0; i < 2; ++i) {
      int ch  = wv * 2 + i;        // 0..7
      int dtl = ch >> 1;           // local d-tile 0..3
      int kc  = ch & 1;            // j-half 0..1
      int ov[4];
      #pragma unroll
      for (int j = 0; j < 4; ++j) {
        int e0 = 2 * j;
        ov[j] = (int)((unsigned int)vtile[kc * 32 + q4 * 8 + e0][dtl * 16 + l16] |
                      ((unsigned int)vtile[kc * 32 + q4 * 8 + e0 + 1][dtl * 16 + l16] << 16));
      }
      intx4 o; o[0] = ov[0]; o[1] = ov[1]; o[2] = ov[2]; o[3] = ov[3];
      size_t off = ((((size_t)b * NJB + (lt >> 6)) * 64) +
                    ((size_t)(dt >> 4) + dtl) * 2 + kc) * 512 + (size_t)ln * 8;
      *(intx4*)(Vfrag + off) = o;
    }
    __syncthreads();
  }
}

// ---------------------------------------------------------------------------
// flash v9 = round-5 dataflow (verified 171 us) with MERGED-PHASE schedule:
//  per iteration: [softmax(jb)] barS [vf+DMA issue; rescale; QK^T(jb+1) ||
//  PV(jb) — one 80-MFMA region with 2 independent chains] barE.
//  PV(jb) and QK^T(jb+1) share no data -> ds_read/vf latency hides under
//  MFMA and the VALU softmax is the only non-overlapped phase (~0.6k cyc).
//  Round-7 lesson: setprio + prefetch-at-top regressed (lockstep m190) —
//  both removed. DMA K(jb+2) issued at TOP of merged region so the barE
//  vmcnt(0) drain lands after ~2.5k cyc of compute.
//  Race audit: Psh write(jb+1) vs read(jb) separated by barE; Ksh DMA(jb+2,
//  buf) vs QK^T read(jb+1, buf^1) disjoint; all DMA >= 1 region before use.
//  grid 256 = b(&7, XCD-pin) x i-tile(16, BI=128) x dh(2, 256-wide D-half).
//  8 waves x 512 thr, __launch_bounds__(512,2) -> 256-VGPR cap, ~130 used
//  (+64 AGPR accum). Round-6 lesson: 32 rows/wave (128 Q regs) spills.
//  RULE-20: all qf/s/O/vf loops fully unrolled.
// ---------------------------------------------------------------------------
__global__ __launch_bounds__(512, 2) void flash8(const float* __restrict__ in,
                                                 const float* __restrict__ qw,
                                                 const unsigned short* __restrict__ Kh,
                                                 const unsigned short* __restrict__ Vfrag,
                                                 const unsigned short* __restrict__ Qh,
                                                 float* __restrict__ out,
                                                 int has_qh) {
  const int bid  = blockIdx.x;
  const int b    = bid & 7;            // batch == XCD (round-robin dispatch)
  const int t2   = bid >> 3;
  const int it_  = t2 & 15;            // i-tile
  const int dh   = t2 >> 4;            // D-half 0..1
  const int i0   = it_ * BI;
  const int tid  = threadIdx.x;
  const int w    = tid >> 6;
  const int lane = tid & 63;
  const int ln16 = lane & 15;
  const int quad = lane >> 4;

  __shared__ unsigned short Ksh[2][BJ][D_];  // 128 KB double-buffered
  __shared__ unsigned short Psh[BI][72];     // 18.4 KB
  __shared__ float Alsh[BI];                 // per-jb rescale alpha
  __shared__ float Lsh[BI];                  // final l

  // ---- Q fragments: rows i0 + w*16 + ln16, full K, A-layout ----
  halfx8 qf[16];
  if (has_qh) {
    const unsigned short* qp =
        Qh + ((size_t)b * L_ + (i0 + w * 16 + ln16)) * D_;
    #pragma unroll
    for (int ks = 0; ks < 16; ++ks)
      qf[ks] = *(const halfx8*)(qp + ks * 32 + quad * 8);
  } else {
    const int qi = i0 + w * 16 + ln16;
    const float* ip = in + ((size_t)b * L_ + qi) * D_;
    const float* wp = qw + (size_t)qi * D_;
    #pragma unroll
    for (int ks = 0; ks < 16; ++ks) {
      int d0 = ks * 32 + quad * 8;
      float4 a0 = *(const float4*)(ip + d0);
      float4 a1 = *(const float4*)(ip + d0 + 4);
      float4 w0 = *(const float4*)(wp + d0);
      float4 w1 = *(const float4*)(wp + d0 + 4);
      halfx8 q;
      q[0] = (_Float16)(a0.x * w0.x * KSCALE);
      q[1] = (_Float16)(a0.y * w0.y * KSCALE);
      q[2] = (_Float16)(a0.z * w0.z * KSCALE);
      q[3] = (_Float16)(a0.w * w0.w * KSCALE);
      q[4] = (_Float16)(a1.x * w1.x * KSCALE);
      q[5] = (_Float16)(a1.y * w1.y * KSCALE);
      q[6] = (_Float16)(a1.z * w1.z * KSCALE);
      q[7] = (_Float16)(a1.w * w1.w * KSCALE);
      qf[ks] = q;
    }
  }

  float m_r[4], l_r[4];
  #pragma unroll
  for (int r = 0; r < 4; ++r) { m_r[r] = -1e30f; l_r[r] = 0.f; }
  floatx4 O[8][2];
  #pragma unroll
  for (int rt = 0; rt < 8; ++rt) {
    O[rt][0] = (floatx4){0.f, 0.f, 0.f, 0.f};
    O[rt][1] = (floatx4){0.f, 0.f, 0.f, 0.f};
  }

  // ---- prologue: DMA K0 -> buf0; QK^T(0); issue DMA K1 -> buf1 ----
  {
    const unsigned short* kb = Kh + ((size_t)b * L_ + w * 8) * D_;
    #pragma unroll
    for (int k = 0; k < 8; ++k) {
      int r = w * 8 + k;
      gld_lds16(kb + (size_t)k * D_ + ((lane ^ (r & 15)) << 3), &Ksh[0][r][0]);
    }
  }
  __syncthreads();

  floatx4 s[4];
  {
    // issue DMA K1 first (drains at barS(0) under QK^T(0)+softmax(0))
    const unsigned short* kb = Kh + ((size_t)b * L_ + BJ + w * 8) * D_;
    #pragma unroll
    for (int k = 0; k < 8; ++k) {
      int r = w * 8 + k;
      gld_lds16(kb + (size_t)k * D_ + ((lane ^ (r & 15)) << 3), &Ksh[1][r][0]);
    }
    s[0] = (floatx4){0.f, 0.f, 0.f, 0.f};
    s[1] = (floatx4){0.f, 0.f, 0.f, 0.f};
    s[2] = (floatx4){0.f, 0.f, 0.f, 0.f};
    s[3] = (floatx4){0.f, 0.f, 0.f, 0.f};
    #pragma unroll
    for (int ks = 0; ks < 16; ++ks) {
      #pragma unroll
      for (int jt = 0; jt < 4; ++jt) {
        halfx8 bk = *(const halfx8*)(
            &Ksh[0][jt * 16 + ln16][((ks * 4 + quad) ^ ln16) << 3]);
        s[jt] = __builtin_amdgcn_mfma_f32_16x16x32_f16(qf[ks], bk, s[jt], 0, 0, 0);
      }
    }
  }

  int buf = 0;  // Ksh[buf] = K(jb) already consumed; Ksh[buf^1] = K(jb+1)
  for (int jb = 0; jb < NJB; ++jb) {
    // ======== softmax(jb): consume s, write Psh/Alsh ========
    #pragma unroll
    for (int r = 0; r < 4; ++r) {
      float mx = fmaxf(fmaxf(s[0][r], s[1][r]), fmaxf(s[2][r], s[3][r]));
      #pragma unroll
      for (int off = 1; off < 16; off <<= 1) mx = fmaxf(mx, __shfl_xor(mx, off));
      float mn = fmaxf(m_r[r], mx);
      float al = exp2f(m_r[r] - mn);   // 1.0 when no update, 0 on first tile
      m_r[r] = mn;
      int row = w * 16 + quad * 4 + r;
      float ls = 0.f;
      #pragma unroll
      for (int jt = 0; jt < 4; ++jt) {
        float p = exp2f(s[jt][r] - mn);
        Psh[row][jt * 16 + ln16] = f2h_bits(p);
        ls += p;
      }
      #pragma unroll
      for (int off = 1; off < 16; off <<= 1) ls += __shfl_xor(ls, off);
      l_r[r] = l_r[r] * al + ls;
      if (ln16 == 0) Alsh[row] = al;
    }
    __syncthreads();  // barS: Psh/Alsh ready; DMA K(jb+1) drained

    // ======== merged region: vf+DMA issue, rescale, QK^T(jb+1) || PV(jb) ==
    // V fragments for PV(jb):
    halfx8 vf[2][2];
    {
      const unsigned short* vb =
          Vfrag + (((size_t)b * NJB + jb) * 64) * 512 + (size_t)lane * 8;
      #pragma unroll
      for (int dt = 0; dt < 2; ++dt)
        #pragma unroll
        for (int kc = 0; kc < 2; ++kc)
          vf[dt][kc] = *(const halfx8*)(
              vb + (size_t)(((dh * 16 + w * 2 + dt) * 2 + kc)) * 512);
    }
    // DMA K(jb+2) into Ksh[buf] (K(jb) fully consumed before barS):
    if (jb + 2 < NJB) {
      const unsigned short* kb =
          Kh + ((size_t)b * L_ + (jb + 2) * BJ + w * 8) * D_;
      #pragma unroll
      for (int k = 0; k < 8; ++k) {
        int r = w * 8 + k;
        gld_lds16(kb + (size_t)k * D_ + ((lane ^ (r & 15)) << 3),
                  &Ksh[buf][r][0]);
      }
    }
    // O rescale by per-row alpha:
    #pragma unroll
    for (int rt = 0; rt < 8; ++rt) {
      float4 alv = *(const float4*)(&Alsh[rt * 16 + quad * 4]);
      #pragma unroll
      for (int dt = 0; dt < 2; ++dt) {
        O[rt][dt][0] *= alv.x; O[rt][dt][1] *= alv.y;
        O[rt][dt][2] *= alv.z; O[rt][dt][3] *= alv.w;
      }
    }
    // QK^T(jb+1) from Ksh[buf^1] (independent of PV below; compiler
    // interleaves the two MFMA chains, hiding ds_read/vf latency):
    if (jb + 1 < NJB) {
      s[0] = (floatx4){0.f, 0.f, 0.f, 0.f};
      s[1] = (floatx4){0.f, 0.f, 0.f, 0.f};
      s[2] = (floatx4){0.f, 0.f, 0.f, 0.f};
      s[3] = (floatx4){0.f, 0.f, 0.f, 0.f};
      #pragma unroll
      for (int ks = 0; ks < 16; ++ks) {
        #pragma unroll
        for (int jt = 0; jt < 4; ++jt) {
          halfx8 bk = *(const halfx8*)(
              &Ksh[buf ^ 1][jt * 16 + ln16][((ks * 4 + quad) ^ ln16) << 3]);
          s[jt] = __builtin_amdgcn_mfma_f32_16x16x32_f16(qf[ks], bk, s[jt], 0, 0, 0);
        }
      }
    }
    // PV(jb): O += P V over this wave's 32-wide d-strip:
    #pragma unroll
    for (int rt = 0; rt < 8; ++rt) {
      #pragma unroll
      for (int kc = 0; kc < 2; ++kc) {
        halfx8 pf = *(const halfx8*)(&Psh[rt * 16 + ln16][kc * 32 + quad * 8]);
        O[rt][0] = __builtin_amdgcn_mfma_f32_16x16x32_f16(pf, vf[0][kc], O[rt][0], 0, 0, 0);
        O[rt][1] = __builtin_amdgcn_mfma_f32_16x16x32_f16(pf, vf[1][kc], O[rt][1], 0, 0, 0);
      }
    }
    __syncthreads();  // barE: Psh reads done; DMA K(jb+2) drained
    buf ^= 1;
  }

  // ---- epilogue: publish l, divide, store this block's D-half ----
  if (ln16 == 0) {
    #pragma unroll
    for (int r = 0; r < 4; ++r) Lsh[w * 16 + quad * 4 + r] = l_r[r];
  }
  __syncthreads();
  #pragma unroll
  for (int rt = 0; rt < 8; ++rt) {
    float4 lv = *(const float4*)(&Lsh[rt * 16 + quad * 4]);
    float i0v = 1.0f / lv.x, i1v = 1.0f / lv.y;
    float i2v = 1.0f / lv.z, i3v = 1.0f / lv.w;
    float* op = out + ((size_t)b * L_ + i0 + rt * 16 + quad * 4) * D_ +
                dh * 256 + w * 32 + ln16;
    #pragma unroll
    for (int dt = 0; dt < 2; ++dt) {
      op[(size_t)0 * D_ + dt * 16] = O[rt][dt][0] * i0v;
      op[(size_t)1 * D_ + dt * 16] = O[rt][dt][1] * i1v;
      op[(size_t)2 * D_ + dt * 16] = O[rt][dt][2] * i2v;
      op[(size_t)3 * D_ + dt * 16] = O[rt][dt][3] * i3v;
    }
  }
}

// ---------------------------------------------------------------------------
extern "C" void kernel_launch(void* const* d_in, const int* in_sizes, int n_in,
                              void* d_out, int out_size, void* d_ws, size_t ws_size,
                              hipStream_t stream) {
  const float* in = (const float*)d_in[0];
  const float* qw = (const float*)d_in[1];
  const float* kw = (const float*)d_in[2];
  const float* vw = (const float*)d_in[3];
  float* out = (float*)d_out;

  const size_t seg = (size_t)B_ * L_ * D_;          // elements per f16 tensor
  unsigned short* Kh = (unsigned short*)d_ws;       // 16.78 MB
  unsigned short* Vf = Kh + seg;                    // 16.78 MB (fragment order)
  unsigned short* Qh = Vf + seg;                    // 16.78 MB (optional)
  const int has_qh = (ws_size >= 3 * seg * sizeof(unsigned short)) ? 1 : 0;

  dim3 gp(L_ / 64, D_ / 64);
  prep_kvq<<<gp, dim3(256), 0, stream>>>(in, qw, kw, vw, Kh, Vf, Qh, has_qh);
  flash8<<<dim3(256), dim3(512), 0, stream>>>(in, qw, Kh, Vf, Qh, out, has_qh);
}